// Round 18
// baseline (86.390 us; speedup 1.0000x reference)
//
#include <hip/hip_runtime.h>

#define WDIM  256
#define NSAMP 512
#define NSIG  32
#define RB    32                 // band rows per block-task
#define NBAND 4096               // NSAMP * (WDIM/RB)
#define QOFF  16                 // ints; queue table q[QOFF..]
#define WOFF  65536              // byte offset of W matrices inside d_ws

typedef float    f32x4 __attribute__((ext_vector_type(4)));
typedef _Float16 f16x8 __attribute__((ext_vector_type(8)));
typedef __fp16   fp16x2 __attribute__((ext_vector_type(2)));

__device__ __forceinline__ int reflect(int q) {
    q = (q < 0) ? (-q - 1) : q;
    return (q >= WDIM) ? (2 * WDIM - 1 - q) : q;
}

// ---- kernel 1 (merged): blocks 0..255 build the 32 reflect-folded banded
// weight matrices W_s[i][r] = wz(r-i)+wz(-r-1-i)+wz(511-r-i) (f16);
// block 256 builds the striped-LPT queue with packed descriptors
// desc = samp | band<<9 | step<<12 | rad<<17.
__global__ __launch_bounds__(256) void build_all(const float* __restrict__ sigmas,
                                                 const int* __restrict__ steps,
                                                 _Float16* __restrict__ Wg,
                                                 int* __restrict__ q) {
    int t = threadIdx.x;
    if (blockIdx.x < 256) {
        __shared__ float wl[161];
        __shared__ float red;
        int s = blockIdx.x >> 3, og = blockIdx.x & 7;
        float sigma = sigmas[s];
        float radf = floorf(4.0f * sigma + 0.5f);
        if (t < 161) {
            float off = (float)(t - 80);
            float w = 0.0f;
            if (fabsf(off) <= radf) { float z = off / sigma; w = expf(-0.5f * z * z); }
            wl[t] = w;
        }
        __syncthreads();
        if (t < 64) {
            float v = wl[t] + wl[t + 64] + (t < 33 ? wl[t + 128] : 0.0f);
            #pragma unroll
            for (int o = 32; o > 0; o >>= 1) v += __shfl_down(v, o);
            if (t == 0) red = 1.0f / v;
        }
        __syncthreads();
        float rs = red;
        int i = t;
        _Float16* wrow = Wg + ((size_t)s << 16) + (i << 8);
        for (int rq = og * 4; rq < og * 4 + 4; ++rq) {
            f16x8 v;
            #pragma unroll
            for (int j = 0; j < 8; ++j) {
                int r = rq * 8 + j;
                int d1 = r - i, d2 = -r - 1 - i, d3 = 511 - r - i;
                float w = 0.0f;
                if (d1 >= -80 && d1 <= 80) w += wl[d1 + 80];
                if (d2 >= -80)             w += wl[d2 + 80];
                if (d3 <= 80)              w += wl[d3 + 80];
                v[j] = (_Float16)(w * rs);
            }
            *(f16x8*)(wrow + rq * 8) = v;
        }
    } else {
        // striped-LPT queue: rank r (heavy-first) -> XCD r&7, slot r>>3;
        // a sample's 8 bands adjacent on the same XCD stripe.
        __shared__ int hist[32];
        __shared__ int base[32];
        if (t < 32) hist[t] = 0;
        __syncthreads();
        int nb2[2], rd2[2], st2[2];
        #pragma unroll
        for (int k = 0; k < 2; ++k) {
            int samp = t + 256 * k;
            int st = steps[samp];
            float sigma = sigmas[st];
            int rad = (int)floorf(4.0f * sigma + 0.5f);
            st2[k] = st; rd2[k] = rad;
            nb2[k] = (2 * rad + 15) >> 3;
            atomicAdd(&hist[nb2[k]], 1);
        }
        __syncthreads();
        if (t == 0) {
            int acc = 0;
            for (int bin = 31; bin >= 0; --bin) { base[bin] = acc; acc += hist[bin]; }
        }
        __syncthreads();
        #pragma unroll
        for (int k = 0; k < 2; ++k) {
            int samp = t + 256 * k;
            int r = atomicAdd(&base[nb2[k]], 1);
            int x = r & 7;
            int p = r >> 3;
            #pragma unroll
            for (int jb = 0; jb < 8; ++jb)
                q[QOFF + (((p << 3) + jb) << 3) + x] =
                    samp | (jb << 9) | (st2[k] << 12) | (rd2[k] << 17);
        }
    }
}

// ---- kernel 2: fused MFMA blur, RB=32 bands. ----
// Phase V: Y = W_band X; A=W rows direct global; B=X column-slices via direct
//          dword loads (pipelined 1 tile) + packed pkrtz cvt. Y -> swizzled LDS.
// Phase H: Z = Y W^T; A=Y from LDS; B=W rows direct, pipelined. f32 out.
template <bool QUEUED>
__global__ __launch_bounds__(256, 2) void blur_mfma(const float* __restrict__ in,
                                                    float* __restrict__ out,
                                                    const float* __restrict__ sigmas,
                                                    const int* __restrict__ steps,
                                                    const int* __restrict__ q,
                                                    const _Float16* __restrict__ Wg) {
    __shared__ alignas(16) _Float16 YL[RB * WDIM];    // 16KB: Y[i][c] swizzled

    int b, r0, s, rad;
    if constexpr (QUEUED) {
        int d = q[QOFF + blockIdx.x];
        b   = d & 511;
        r0  = ((d >> 9) & 7) << 5;
        s   = (d >> 12) & 31;
        rad = (d >> 17) & 127;
    } else {
        int bid = blockIdx.x;
        int e = (bid & 7) * (NBAND / 8) + (bid >> 3);
        b = e >> 3; r0 = (e & 7) << 5;
        s = steps[b];
        rad = (int)floorf(4.0f * sigmas[s] + 0.5f);
    }
    const _Float16* Wm = Wg + ((size_t)s << 16);
    const float*    Xb = in + ((size_t)b << 16);

    int ln = threadIdx.x & 63, wv = threadIdx.x >> 6;
    int lm = ln & 15, lq = ln >> 4;

    // ---------------- Phase V: Y[i][c] = sum_r W[r0+i][r] X[r][c] ----------------
    f32x4 acc[2][4];
    #pragma unroll
    for (int mt = 0; mt < 2; ++mt)
        #pragma unroll
        for (int nt = 0; nt < 4; ++nt) acc[mt][nt] = (f32x4)0.0f;

    int kt0 = max(0, r0 - rad) >> 5;
    int kt1 = min(WDIM - 1, r0 + RB - 1 + rad) >> 5;

    float xvc[4][8], xvn[4][8];
    auto xload = [&](int kt, float (&dst)[4][8]) {
        const float* xp = Xb + (size_t)((kt << 5) + lq * 8) * WDIM + wv * 64 + lm;
        #pragma unroll
        for (int nt = 0; nt < 4; ++nt)
            #pragma unroll
            for (int jj = 0; jj < 8; ++jj)
                dst[nt][jj] = xp[(size_t)jj * WDIM + nt * 16];
    };
    auto vtile = [&](int kt, float (&xv)[4][8]) {
        f16x8 af[2];
        #pragma unroll
        for (int mt = 0; mt < 2; ++mt)
            af[mt] = *(const f16x8*)(Wm + (size_t)(r0 + mt * 16 + lm) * WDIM + (kt << 5) + lq * 8);
        #pragma unroll
        for (int nt = 0; nt < 4; ++nt) {
            union { f16x8 v; fp16x2 h[4]; } u;
            #pragma unroll
            for (int p = 0; p < 4; ++p)
                u.h[p] = __builtin_amdgcn_cvt_pkrtz(xv[nt][2 * p], xv[nt][2 * p + 1]);
            #pragma unroll
            for (int mt = 0; mt < 2; ++mt)
                acc[mt][nt] = __builtin_amdgcn_mfma_f32_16x16x32_f16(af[mt], u.v, acc[mt][nt], 0, 0, 0);
        }
    };

    xload(kt0, xvc);
    for (int kt = kt0; kt <= kt1; ++kt) {
        if (kt < kt1) xload(kt + 1, xvn);
        vtile(kt, xvc);
        if (kt < kt1) {
            #pragma unroll
            for (int nt = 0; nt < 4; ++nt)
                #pragma unroll
                for (int jj = 0; jj < 8; ++jj) xvc[nt][jj] = xvn[nt][jj];
        }
    }

    // write Y to swizzled LDS: D layout row=(lq*4+g), col=lm per 16x16 tile
    #pragma unroll
    for (int mt = 0; mt < 2; ++mt)
        #pragma unroll
        for (int nt = 0; nt < 4; ++nt)
            #pragma unroll
            for (int g = 0; g < 4; ++g) {
                int i = mt * 16 + lq * 4 + g;
                int c = wv * 64 + nt * 16 + lm;
                YL[(i << 8) + (c ^ ((i & 7) << 3))] = (_Float16)acc[mt][nt][g];
            }

    // ---------------- Phase H: Z[i][j] = sum_c Y[i][c] W[j][c] ----------------
    int jlo = wv * 64;
    int hk0 = max(0, jlo - rad) >> 5;
    int hk1 = min(WDIM - 1, jlo + 63 + rad) >> 5;

    f16x8 bfc[4], bfn[4];
    auto wload = [&](int kt, f16x8 (&bf)[4]) {
        #pragma unroll
        for (int nt = 0; nt < 4; ++nt)
            bf[nt] = *(const f16x8*)(Wm + (size_t)(jlo + nt * 16 + lm) * WDIM + (kt << 5) + lq * 8);
    };
    wload(hk0, bfc);                       // issued BEFORE the barrier (global-only)
    __syncthreads();

    f32x4 hac[2][4];
    #pragma unroll
    for (int mt = 0; mt < 2; ++mt)
        #pragma unroll
        for (int nt = 0; nt < 4; ++nt) hac[mt][nt] = (f32x4)0.0f;

    for (int kt = hk0; kt <= hk1; ++kt) {
        if (kt < hk1) wload(kt + 1, bfn);
        f16x8 af[2];
        #pragma unroll
        for (int mt = 0; mt < 2; ++mt) {
            int i = mt * 16 + lm;
            int c0 = (kt << 5) + lq * 8;
            af[mt] = *(const f16x8*)&YL[(i << 8) + (c0 ^ ((i & 7) << 3))];
        }
        #pragma unroll
        for (int mt = 0; mt < 2; ++mt)
            #pragma unroll
            for (int nt = 0; nt < 4; ++nt)
                hac[mt][nt] = __builtin_amdgcn_mfma_f32_16x16x32_f16(af[mt], bfc[nt], hac[mt][nt], 0, 0, 0);
        if (kt < hk1) {
            #pragma unroll
            for (int nt = 0; nt < 4; ++nt) bfc[nt] = bfn[nt];
        }
    }

    float* ob = out + ((size_t)b << 16);
    #pragma unroll
    for (int mt = 0; mt < 2; ++mt)
        #pragma unroll
        for (int nt = 0; nt < 4; ++nt)
            #pragma unroll
            for (int g = 0; g < 4; ++g)
                ob[(size_t)(r0 + mt * 16 + lq * 4 + g) * WDIM + jlo + nt * 16 + lm] = hac[mt][nt][g];
}

// ---------- fallback path (only if ws too small; needs no workspace) ----------
__device__ __forceinline__ int make_weights161(int b, const float* __restrict__ sigmas,
                                               const int* __restrict__ steps,
                                               float* wl, float* red) {
    int t = threadIdx.x;
    float sigma = sigmas[steps[b]];
    float radf = floorf(4.0f * sigma + 0.5f);
    if (t < 192) {
        float w = 0.0f;
        if (t < 161) {
            float off = (float)(t - 80);
            if (fabsf(off) <= radf) { float z = off / sigma; w = expf(-0.5f * z * z); }
        }
        wl[t] = w;
    }
    __syncthreads();
    if (t < 64) {
        float v = wl[t] + wl[t + 64] + wl[t + 128];
        #pragma unroll
        for (int o = 32; o > 0; o >>= 1) v += __shfl_down(v, o);
        if (t == 0) red[0] = 1.0f / v;
    }
    __syncthreads();
    float rs = red[0];
    if (t < 161) wl[t] *= rs;
    __syncthreads();
    return (int)radf;
}

__global__ __launch_bounds__(256) void vblur_nt(const float* __restrict__ in,
                                                float* __restrict__ out,
                                                const float* __restrict__ sigmas,
                                                const int* __restrict__ steps) {
    __shared__ float wl[192];
    __shared__ float red[1];
    int bid = blockIdx.x;
    int b = bid >> 4, i0 = (bid & 15) * 16;
    int rad = make_weights161(b, sigmas, steps, wl, red);
    int j = threadIdx.x;
    const float* inb = in + (size_t)b * WDIM * WDIM;
    float acc[16];
    #pragma unroll
    for (int ii = 0; ii < 16; ++ii) acc[ii] = 0.0f;
    for (int u = -rad; u <= rad; ++u) {
        float w = wl[80 + u];
        #pragma unroll
        for (int ii = 0; ii < 16; ++ii)
            acc[ii] = fmaf(w, inb[reflect(i0 + ii + u) * WDIM + j], acc[ii]);
    }
    #pragma unroll
    for (int ii = 0; ii < 16; ++ii)
        out[((size_t)b * WDIM + (i0 + ii)) * WDIM + j] = acc[ii];
}

__global__ __launch_bounds__(256) void hblur_inplace(float* __restrict__ buf,
                                                     const float* __restrict__ sigmas,
                                                     const int* __restrict__ steps) {
    __shared__ float wl[192];
    __shared__ float red[1];
    __shared__ float rp[WDIM + 160];
    int bid = blockIdx.x;
    int b = bid >> 8, i = bid & 255;
    float* row = buf + ((size_t)b * WDIM + i) * WDIM;
    int t = threadIdx.x;
    for (int s = t; s < WDIM + 160; s += 256) rp[s] = row[reflect(s - 80)];
    int rad = make_weights161(b, sigmas, steps, wl, red);
    float acc = 0.0f;
    for (int u = -rad; u <= rad; ++u) acc = fmaf(wl[80 + u], rp[80 + t + u], acc);
    row[t] = acc;
}
// --------------------------------------------------------------------------------

extern "C" void kernel_launch(void* const* d_in, const int* in_sizes, int n_in,
                              void* d_out, int out_size, void* d_ws, size_t ws_size,
                              hipStream_t stream) {
    const float* x     = (const float*)d_in[0];
    const float* sig   = (const float*)d_in[1];
    const int*   steps = (const int*)d_in[2];
    float* out = (float*)d_out;

    const size_t need = (size_t)WOFF + (size_t)NSIG * WDIM * WDIM * 2;
    if (ws_size >= need) {
        int* q = (int*)d_ws;
        _Float16* Wg = (_Float16*)((char*)d_ws + WOFF);
        build_all<<<257, 256, 0, stream>>>(sig, steps, Wg, q);
        blur_mfma<true><<<NBAND, 256, 0, stream>>>(x, out, sig, steps, q, Wg);
    } else {
        vblur_nt<<<NSAMP * 16, 256, 0, stream>>>(x, out, sig, steps);
        hblur_inplace<<<NSAMP * WDIM, 256, 0, stream>>>(out, sig, steps);
    }
}

// Round 19
// 85.965 us; speedup vs baseline: 1.0049x; 1.0049x over previous
//
#include <hip/hip_runtime.h>

#define WDIM  256
#define NSAMP 512
#define NSIG  32
#define RB    32                 // band rows per block-task
#define NBAND 4096               // NSAMP * (WDIM/RB)
#define QOFF  16                 // ints; queue table q[QOFF..]
#define WOFF  65536              // byte offset of W matrices inside d_ws
#define MAXT  7                  // max 32-wide K-tiles per phase (span<=224)

typedef float    f32x4 __attribute__((ext_vector_type(4)));
typedef _Float16 f16x8 __attribute__((ext_vector_type(8)));
typedef __fp16   fp16x2 __attribute__((ext_vector_type(2)));

__device__ __forceinline__ int reflect(int q) {
    q = (q < 0) ? (-q - 1) : q;
    return (q >= WDIM) ? (2 * WDIM - 1 - q) : q;
}

// ---- kernel 1 (merged): blocks 0..255 build W matrices; block 256 the queue.
// W_s[i][r] = wz(r-i)+wz(-r-1-i)+wz(511-r-i); desc = samp|band<<9|step<<12|rad<<17.
__global__ __launch_bounds__(256) void build_all(const float* __restrict__ sigmas,
                                                 const int* __restrict__ steps,
                                                 _Float16* __restrict__ Wg,
                                                 int* __restrict__ q) {
    int t = threadIdx.x;
    if (blockIdx.x < 256) {
        __shared__ float wl[161];
        __shared__ float red;
        int s = blockIdx.x >> 3, og = blockIdx.x & 7;
        float sigma = sigmas[s];
        float radf = floorf(4.0f * sigma + 0.5f);
        if (t < 161) {
            float off = (float)(t - 80);
            float w = 0.0f;
            if (fabsf(off) <= radf) { float z = off / sigma; w = expf(-0.5f * z * z); }
            wl[t] = w;
        }
        __syncthreads();
        if (t < 64) {
            float v = wl[t] + wl[t + 64] + (t < 33 ? wl[t + 128] : 0.0f);
            #pragma unroll
            for (int o = 32; o > 0; o >>= 1) v += __shfl_down(v, o);
            if (t == 0) red = 1.0f / v;
        }
        __syncthreads();
        float rs = red;
        int i = t;
        _Float16* wrow = Wg + ((size_t)s << 16) + (i << 8);
        for (int rq = og * 4; rq < og * 4 + 4; ++rq) {
            f16x8 v;
            #pragma unroll
            for (int j = 0; j < 8; ++j) {
                int r = rq * 8 + j;
                int d1 = r - i, d2 = -r - 1 - i, d3 = 511 - r - i;
                float w = 0.0f;
                if (d1 >= -80 && d1 <= 80) w += wl[d1 + 80];
                if (d2 >= -80)             w += wl[d2 + 80];
                if (d3 <= 80)              w += wl[d3 + 80];
                v[j] = (_Float16)(w * rs);
            }
            *(f16x8*)(wrow + rq * 8) = v;
        }
    } else {
        __shared__ int hist[32];
        __shared__ int base[32];
        if (t < 32) hist[t] = 0;
        __syncthreads();
        int nb2[2], rd2[2], st2[2];
        #pragma unroll
        for (int k = 0; k < 2; ++k) {
            int samp = t + 256 * k;
            int st = steps[samp];
            float sigma = sigmas[st];
            int rad = (int)floorf(4.0f * sigma + 0.5f);
            st2[k] = st; rd2[k] = rad;
            nb2[k] = (2 * rad + 15) >> 3;
            atomicAdd(&hist[nb2[k]], 1);
        }
        __syncthreads();
        if (t == 0) {
            int acc = 0;
            for (int bin = 31; bin >= 0; --bin) { base[bin] = acc; acc += hist[bin]; }
        }
        __syncthreads();
        #pragma unroll
        for (int k = 0; k < 2; ++k) {
            int samp = t + 256 * k;
            int r = atomicAdd(&base[nb2[k]], 1);
            int x = r & 7;
            int p = r >> 3;
            #pragma unroll
            for (int jb = 0; jb < 8; ++jb)
                q[QOFF + (((p << 3) + jb) << 3) + x] =
                    samp | (jb << 9) | (st2[k] << 12) | (rd2[k] << 17);
        }
    }
}

// ---- kernel 2: fused MFMA blur; ALL global streams pipelined 1-deep, ----
// first tiles of V (af,X) and H (bf) issued at block start; loops static-unrolled.
template <bool QUEUED>
__global__ __launch_bounds__(256, 3) void blur_mfma(const float* __restrict__ in,
                                                    float* __restrict__ out,
                                                    const float* __restrict__ sigmas,
                                                    const int* __restrict__ steps,
                                                    const int* __restrict__ q,
                                                    const _Float16* __restrict__ Wg) {
    __shared__ alignas(16) _Float16 YL[RB * WDIM];    // 16KB: Y[i][c] swizzled

    int b, r0, s, rad;
    if constexpr (QUEUED) {
        int d = q[QOFF + blockIdx.x];
        b   = d & 511;
        r0  = ((d >> 9) & 7) << 5;
        s   = (d >> 12) & 31;
        rad = (d >> 17) & 127;
    } else {
        int bid = blockIdx.x;
        int e = (bid & 7) * (NBAND / 8) + (bid >> 3);
        b = e >> 3; r0 = (e & 7) << 5;
        s = steps[b];
        rad = (int)floorf(4.0f * sigmas[s] + 0.5f);
    }
    const _Float16* Wm = Wg + ((size_t)s << 16);
    const float*    Xb = in + ((size_t)b << 16);

    int ln = threadIdx.x & 63, wv = threadIdx.x >> 6;
    int lm = ln & 15, lq = ln >> 4;

    int kt0 = max(0, r0 - rad) >> 5;
    int kt1 = min(WDIM - 1, r0 + RB - 1 + rad) >> 5;
    int ktn = kt1 - kt0;                    // 0..MAXT-1
    int jlo = wv * 64;
    int hk0 = max(0, jlo - rad) >> 5;
    int hk1 = min(WDIM - 1, jlo + 63 + rad) >> 5;
    int htn = hk1 - hk0;

    f32x4 acc[2][4];
    #pragma unroll
    for (int mt = 0; mt < 2; ++mt)
        #pragma unroll
        for (int nt = 0; nt < 4; ++nt) acc[mt][nt] = (f32x4)0.0f;

    float xva[4][8], xvb[4][8];
    f16x8 afa[2], afb[2], bfa[4], bfb[4];

    auto xload = [&](int kt, float (&dst)[4][8]) {
        const float* xp = Xb + (size_t)((kt << 5) + lq * 8) * WDIM + wv * 64 + lm;
        #pragma unroll
        for (int nt = 0; nt < 4; ++nt)
            #pragma unroll
            for (int jj = 0; jj < 8; ++jj)
                dst[nt][jj] = xp[(size_t)jj * WDIM + nt * 16];
    };
    auto afload = [&](int kt, f16x8 (&af)[2]) {
        #pragma unroll
        for (int mt = 0; mt < 2; ++mt)
            af[mt] = *(const f16x8*)(Wm + (size_t)(r0 + mt * 16 + lm) * WDIM + (kt << 5) + lq * 8);
    };
    auto wload = [&](int kt, f16x8 (&bf)[4]) {
        #pragma unroll
        for (int nt = 0; nt < 4; ++nt)
            bf[nt] = *(const f16x8*)(Wm + (size_t)(jlo + nt * 16 + lm) * WDIM + (kt << 5) + lq * 8);
    };
    auto vtile = [&](f16x8 (&af)[2], float (&xv)[4][8]) {
        #pragma unroll
        for (int nt = 0; nt < 4; ++nt) {
            union { f16x8 v; fp16x2 h[4]; } u;
            #pragma unroll
            for (int p = 0; p < 4; ++p)
                u.h[p] = __builtin_amdgcn_cvt_pkrtz(xv[nt][2 * p], xv[nt][2 * p + 1]);
            #pragma unroll
            for (int mt = 0; mt < 2; ++mt)
                acc[mt][nt] = __builtin_amdgcn_mfma_f32_16x16x32_f16(af[mt], u.v, acc[mt][nt], 0, 0, 0);
        }
    };

    // ---- block-start issue burst: V tile0 (af+X) and H tile0 (bf) ----
    afload(kt0, afa);
    xload(kt0, xva);
    wload(hk0, bfa);

    // ---------------- Phase V (static-unrolled, all streams 1-deep) ----------------
    #pragma unroll
    for (int kti = 0; kti < MAXT; ++kti) {
        if (kti > ktn) break;
        int kt = kt0 + kti;
        if ((kti & 1) == 0) {
            if (kti < ktn) { afload(kt + 1, afb); xload(kt + 1, xvb); }
            vtile(afa, xva);
        } else {
            if (kti < ktn) { afload(kt + 1, afa); xload(kt + 1, xva); }
            vtile(afb, xvb);
        }
    }

    // write Y to swizzled LDS: D layout row=(lq*4+g), col=lm per 16x16 tile
    #pragma unroll
    for (int mt = 0; mt < 2; ++mt)
        #pragma unroll
        for (int nt = 0; nt < 4; ++nt)
            #pragma unroll
            for (int g = 0; g < 4; ++g) {
                int i = mt * 16 + lq * 4 + g;
                int c = wv * 64 + nt * 16 + lm;
                YL[(i << 8) + (c ^ ((i & 7) << 3))] = (_Float16)acc[mt][nt][g];
            }
    __syncthreads();

    // ---------------- Phase H (static-unrolled, bf 1-deep, tile0 pre-issued) ----------------
    f32x4 hac[2][4];
    #pragma unroll
    for (int mt = 0; mt < 2; ++mt)
        #pragma unroll
        for (int nt = 0; nt < 4; ++nt) hac[mt][nt] = (f32x4)0.0f;

    auto htile = [&](int kt, f16x8 (&bf)[4]) {
        f16x8 af[2];
        #pragma unroll
        for (int mt = 0; mt < 2; ++mt) {
            int i = mt * 16 + lm;
            int c0 = (kt << 5) + lq * 8;
            af[mt] = *(const f16x8*)&YL[(i << 8) + (c0 ^ ((i & 7) << 3))];
        }
        #pragma unroll
        for (int mt = 0; mt < 2; ++mt)
            #pragma unroll
            for (int nt = 0; nt < 4; ++nt)
                hac[mt][nt] = __builtin_amdgcn_mfma_f32_16x16x32_f16(af[mt], bf[nt], hac[mt][nt], 0, 0, 0);
    };

    #pragma unroll
    for (int hti = 0; hti < MAXT; ++hti) {
        if (hti > htn) break;
        int kt = hk0 + hti;
        if ((hti & 1) == 0) {
            if (hti < htn) wload(kt + 1, bfb);
            htile(kt, bfa);
        } else {
            if (hti < htn) wload(kt + 1, bfa);
            htile(kt, bfb);
        }
    }

    float* ob = out + ((size_t)b << 16);
    #pragma unroll
    for (int mt = 0; mt < 2; ++mt)
        #pragma unroll
        for (int nt = 0; nt < 4; ++nt)
            #pragma unroll
            for (int g = 0; g < 4; ++g)
                ob[(size_t)(r0 + mt * 16 + lq * 4 + g) * WDIM + jlo + nt * 16 + lm] = hac[mt][nt][g];
}

// ---------- fallback path (only if ws too small; needs no workspace) ----------
__device__ __forceinline__ int make_weights161(int b, const float* __restrict__ sigmas,
                                               const int* __restrict__ steps,
                                               float* wl, float* red) {
    int t = threadIdx.x;
    float sigma = sigmas[steps[b]];
    float radf = floorf(4.0f * sigma + 0.5f);
    if (t < 192) {
        float w = 0.0f;
        if (t < 161) {
            float off = (float)(t - 80);
            if (fabsf(off) <= radf) { float z = off / sigma; w = expf(-0.5f * z * z); }
        }
        wl[t] = w;
    }
    __syncthreads();
    if (t < 64) {
        float v = wl[t] + wl[t + 64] + wl[t + 128];
        #pragma unroll
        for (int o = 32; o > 0; o >>= 1) v += __shfl_down(v, o);
        if (t == 0) red[0] = 1.0f / v;
    }
    __syncthreads();
    float rs = red[0];
    if (t < 161) wl[t] *= rs;
    __syncthreads();
    return (int)radf;
}

__global__ __launch_bounds__(256) void vblur_nt(const float* __restrict__ in,
                                                float* __restrict__ out,
                                                const float* __restrict__ sigmas,
                                                const int* __restrict__ steps) {
    __shared__ float wl[192];
    __shared__ float red[1];
    int bid = blockIdx.x;
    int b = bid >> 4, i0 = (bid & 15) * 16;
    int rad = make_weights161(b, sigmas, steps, wl, red);
    int j = threadIdx.x;
    const float* inb = in + (size_t)b * WDIM * WDIM;
    float acc[16];
    #pragma unroll
    for (int ii = 0; ii < 16; ++ii) acc[ii] = 0.0f;
    for (int u = -rad; u <= rad; ++u) {
        float w = wl[80 + u];
        #pragma unroll
        for (int ii = 0; ii < 16; ++ii)
            acc[ii] = fmaf(w, inb[reflect(i0 + ii + u) * WDIM + j], acc[ii]);
    }
    #pragma unroll
    for (int ii = 0; ii < 16; ++ii)
        out[((size_t)b * WDIM + (i0 + ii)) * WDIM + j] = acc[ii];
}

__global__ __launch_bounds__(256) void hblur_inplace(float* __restrict__ buf,
                                                     const float* __restrict__ sigmas,
                                                     const int* __restrict__ steps) {
    __shared__ float wl[192];
    __shared__ float red[1];
    __shared__ float rp[WDIM + 160];
    int bid = blockIdx.x;
    int b = bid >> 8, i = bid & 255;
    float* row = buf + ((size_t)b * WDIM + i) * WDIM;
    int t = threadIdx.x;
    for (int s = t; s < WDIM + 160; s += 256) rp[s] = row[reflect(s - 80)];
    int rad = make_weights161(b, sigmas, steps, wl, red);
    float acc = 0.0f;
    for (int u = -rad; u <= rad; ++u) acc = fmaf(wl[80 + u], rp[80 + t + u], acc);
    row[t] = acc;
}
// --------------------------------------------------------------------------------

extern "C" void kernel_launch(void* const* d_in, const int* in_sizes, int n_in,
                              void* d_out, int out_size, void* d_ws, size_t ws_size,
                              hipStream_t stream) {
    const float* x     = (const float*)d_in[0];
    const float* sig   = (const float*)d_in[1];
    const int*   steps = (const int*)d_in[2];
    float* out = (float*)d_out;

    const size_t need = (size_t)WOFF + (size_t)NSIG * WDIM * WDIM * 2;
    if (ws_size >= need) {
        int* q = (int*)d_ws;
        _Float16* Wg = (_Float16*)((char*)d_ws + WOFF);
        build_all<<<257, 256, 0, stream>>>(sig, steps, Wg, q);
        blur_mfma<true><<<NBAND, 256, 0, stream>>>(x, out, sig, steps, q, Wg);
    } else {
        vblur_nt<<<NSAMP * 16, 256, 0, stream>>>(x, out, sig, steps);
        hblur_inplace<<<NSAMP * WDIM, 256, 0, stream>>>(out, sig, steps);
    }
}

// Round 20
// 73.448 us; speedup vs baseline: 1.1762x; 1.1704x over previous
//
#include <hip/hip_runtime.h>

#define WDIM  256
#define NSAMP 512
#define NSIG  32
#define NBLK  2048               // 512 samples x 4 j-quarters
#define QOFF  16                 // ints; queue table q[QOFF..]
#define WOFF  65536              // byte offset of W matrices inside d_ws

typedef float    f32x4 __attribute__((ext_vector_type(4)));
typedef _Float16 f16x4 __attribute__((ext_vector_type(4)));
typedef _Float16 f16x8 __attribute__((ext_vector_type(8)));
typedef __fp16   fp16x2 __attribute__((ext_vector_type(2)));

__device__ __forceinline__ int reflect(int q) {
    q = (q < 0) ? (-q - 1) : q;
    return (q >= WDIM) ? (2 * WDIM - 1 - q) : q;
}

// ---- kernel 1 (merged): blocks 0..255 build W matrices; block 256 the queue.
// W_s[i][r] = wz(r-i)+wz(-r-1-i)+wz(511-r-i); desc = samp|jb<<9|step<<11|rad<<16.
__global__ __launch_bounds__(256) void build_all(const float* __restrict__ sigmas,
                                                 const int* __restrict__ steps,
                                                 _Float16* __restrict__ Wg,
                                                 int* __restrict__ q) {
    int t = threadIdx.x;
    if (blockIdx.x < 256) {
        __shared__ float wl[161];
        __shared__ float red;
        int s = blockIdx.x >> 3, og = blockIdx.x & 7;
        float sigma = sigmas[s];
        float radf = floorf(4.0f * sigma + 0.5f);
        if (t < 161) {
            float off = (float)(t - 80);
            float w = 0.0f;
            if (fabsf(off) <= radf) { float z = off / sigma; w = expf(-0.5f * z * z); }
            wl[t] = w;
        }
        __syncthreads();
        if (t < 64) {
            float v = wl[t] + wl[t + 64] + (t < 33 ? wl[t + 128] : 0.0f);
            #pragma unroll
            for (int o = 32; o > 0; o >>= 1) v += __shfl_down(v, o);
            if (t == 0) red = 1.0f / v;
        }
        __syncthreads();
        float rs = red;
        int i = t;
        _Float16* wrow = Wg + ((size_t)s << 16) + (i << 8);
        for (int rq = og * 4; rq < og * 4 + 4; ++rq) {
            f16x8 v;
            #pragma unroll
            for (int j = 0; j < 8; ++j) {
                int r = rq * 8 + j;
                int d1 = r - i, d2 = -r - 1 - i, d3 = 511 - r - i;
                float w = 0.0f;
                if (d1 >= -80 && d1 <= 80) w += wl[d1 + 80];
                if (d2 >= -80)             w += wl[d2 + 80];
                if (d3 <= 80)              w += wl[d3 + 80];
                v[j] = (_Float16)(w * rs);
            }
            *(f16x8*)(wrow + rq * 8) = v;
        }
    } else {
        __shared__ int hist[32];
        __shared__ int base[32];
        if (t < 32) hist[t] = 0;
        __syncthreads();
        int nb2[2], rd2[2], st2[2];
        #pragma unroll
        for (int k = 0; k < 2; ++k) {
            int samp = t + 256 * k;
            int st = steps[samp];
            float sigma = sigmas[st];
            int rad = (int)floorf(4.0f * sigma + 0.5f);
            st2[k] = st; rd2[k] = rad;
            nb2[k] = (2 * rad + 15) >> 3;
            atomicAdd(&hist[nb2[k]], 1);
        }
        __syncthreads();
        if (t == 0) {
            int acc = 0;
            for (int bin = 31; bin >= 0; --bin) { base[bin] = acc; acc += hist[bin]; }
        }
        __syncthreads();
        #pragma unroll
        for (int k = 0; k < 2; ++k) {
            int samp = t + 256 * k;
            int r = atomicAdd(&base[nb2[k]], 1);
            int x = r & 7;
            int p = r >> 3;
            #pragma unroll
            for (int jb = 0; jb < 4; ++jb)
                q[QOFF + (((p << 2) + jb) << 3) + x] =
                    samp | (jb << 9) | (st2[k] << 11) | (rd2[k] << 16);
        }
    }
}

// ---- kernel 2: fused MFMA blur, H-FIRST, block = [256 rows x 64-col quarter].
// Phase H: Yh[r][j] = sum_c X[r][c] W[j][c]; A=X staged LDS (f32->f16 swizzled),
//          B=W j-rows staged LDS; frags via ds_read_b128; Yh^T -> LDS YT.
// Phase V: Z[i][j] = sum_r W[i][r] Yh[r][j]; A=W rows direct global (64B rows),
//          B=YT LDS b128; banded per-mt K range. One barrier pair per H K-tile.
template <bool QUEUED>
__global__ __launch_bounds__(256, 3) void blur_mfma(const float* __restrict__ in,
                                                    float* __restrict__ out,
                                                    const float* __restrict__ sigmas,
                                                    const int* __restrict__ steps,
                                                    const int* __restrict__ q,
                                                    const _Float16* __restrict__ Wg) {
    __shared__ alignas(16) _Float16 XL[256 * 32];   // 16 KB: X K-tile, swizzled
    __shared__ alignas(16) _Float16 WH[64 * 32];    //  4 KB: W j-rows K-tile
    __shared__ alignas(16) _Float16 YT[64 * 256];   // 32 KB: Yh^T, swizzled

    int b, j0, s, rad;
    if constexpr (QUEUED) {
        int d = q[QOFF + blockIdx.x];
        b   = d & 511;
        j0  = ((d >> 9) & 3) << 6;
        s   = (d >> 11) & 31;
        rad = (d >> 16) & 127;
    } else {
        int bid = blockIdx.x;
        int e = (bid & 7) * (NBLK / 8) + (bid >> 3);
        b = e >> 2; j0 = (e & 3) << 6;
        s = steps[b];
        rad = (int)floorf(4.0f * sigmas[s] + 0.5f);
    }
    const _Float16* Wm = Wg + ((size_t)s << 16);
    const float*    Xb = in + ((size_t)b << 16);

    int tt = threadIdx.x;
    int ln = tt & 63, wv = tt >> 6;
    int lm = ln & 15, lq = ln >> 4;

    // staging decomposition
    int sr = tt >> 3;             // X stage row base (0..31)
    int sc = (tt & 7) * 4;        // X stage col (0,4..28)
    int sj = tt >> 2;             // W stage j (0..63)
    int sw8 = (tt & 3) * 8;       // W stage c chunk

    int kh0 = max(0, j0 - rad) >> 5;
    int kh1 = min(WDIM - 1, j0 + 63 + rad) >> 5;

    f32x4 xs[8];
    f16x8 wst;
    auto ldstage = [&](int kt) {     // issue global loads into registers
        const float* xp = Xb + (size_t)sr * WDIM + (kt << 5) + sc;
        #pragma unroll
        for (int k = 0; k < 8; ++k)
            xs[k] = *(const f32x4*)(xp + (size_t)(k * 32) * WDIM);
        wst = *(const f16x8*)(Wm + (size_t)(j0 + sj) * WDIM + (kt << 5) + sw8);
    };
    auto wrstage = [&]() {           // convert + swizzled LDS writes
        #pragma unroll
        for (int k = 0; k < 8; ++k) {
            int rr = sr + 32 * k;
            union { f16x4 v; fp16x2 h[2]; } u;
            u.h[0] = __builtin_amdgcn_cvt_pkrtz(xs[k][0], xs[k][1]);
            u.h[1] = __builtin_amdgcn_cvt_pkrtz(xs[k][2], xs[k][3]);
            *(f16x4*)&XL[rr * 32 + ((((sc >> 3) ^ (rr & 3)) << 3) + (sc & 7))] = u.v;
        }
        *(f16x8*)&WH[sj * 32 + (((tt & 3) ^ (sj & 3)) << 3)] = wst;
    };

    // ---------------- Phase H ----------------
    f32x4 acc[4][4];
    #pragma unroll
    for (int mt = 0; mt < 4; ++mt)
        #pragma unroll
        for (int nt = 0; nt < 4; ++nt) acc[mt][nt] = (f32x4)0.0f;

    ldstage(kh0);
    for (int kt = kh0; kt <= kh1; ++kt) {
        wrstage();
        __syncthreads();                       // tiles visible
        if (kt < kh1) ldstage(kt + 1);         // issue next, covered by compute
        f16x8 bf[4];
        #pragma unroll
        for (int nt = 0; nt < 4; ++nt) {
            int j = nt * 16 + lm;
            bf[nt] = *(const f16x8*)&WH[j * 32 + ((lq ^ (j & 3)) << 3)];
        }
        #pragma unroll
        for (int mt = 0; mt < 4; ++mt) {
            int r = wv * 64 + mt * 16 + lm;
            f16x8 af = *(const f16x8*)&XL[r * 32 + ((lq ^ (r & 3)) << 3)];
            #pragma unroll
            for (int nt = 0; nt < 4; ++nt)
                acc[mt][nt] = __builtin_amdgcn_mfma_f32_16x16x32_f16(af, bf[nt], acc[mt][nt], 0, 0, 0);
        }
        __syncthreads();                       // compute done before next write
    }

    // Yh^T -> YT (swizzled): D row=(lq*4+g)->r, col=lm->j
    #pragma unroll
    for (int mt = 0; mt < 4; ++mt)
        #pragma unroll
        for (int nt = 0; nt < 4; ++nt) {
            int r4 = wv * 64 + mt * 16 + lq * 4;
            int j  = nt * 16 + lm;
            union { f16x4 v; fp16x2 h[2]; } u;
            u.h[0] = __builtin_amdgcn_cvt_pkrtz(acc[mt][nt][0], acc[mt][nt][1]);
            u.h[1] = __builtin_amdgcn_cvt_pkrtz(acc[mt][nt][2], acc[mt][nt][3]);
            *(f16x4*)&YT[j * 256 + ((((r4 >> 3) ^ (j & 7)) << 3) + (r4 & 7))] = u.v;
        }
    __syncthreads();

    // ---------------- Phase V ----------------
    f32x4 hac[4][4];
    #pragma unroll
    for (int mt = 0; mt < 4; ++mt)
        #pragma unroll
        for (int nt = 0; nt < 4; ++nt) hac[mt][nt] = (f32x4)0.0f;

    int ka[4], kb[4];
    #pragma unroll
    for (int mt = 0; mt < 4; ++mt) {
        int i0m = wv * 64 + mt * 16;
        ka[mt] = max(0, i0m - rad) >> 5;
        kb[mt] = min(WDIM - 1, i0m + 15 + rad) >> 5;
    }

    for (int kt = ka[0]; kt <= kb[3]; ++kt) {
        f16x8 bf[4];
        #pragma unroll
        for (int nt = 0; nt < 4; ++nt) {
            int j = nt * 16 + lm;
            bf[nt] = *(const f16x8*)&YT[j * 256 + ((((kt << 2) + lq) ^ (j & 7)) << 3)];
        }
        #pragma unroll
        for (int mt = 0; mt < 4; ++mt) {
            if (kt >= ka[mt] && kt <= kb[mt]) {
                f16x8 af = *(const f16x8*)(Wm + (size_t)(wv * 64 + mt * 16 + lm) * WDIM + (kt << 5) + lq * 8);
                #pragma unroll
                for (int nt = 0; nt < 4; ++nt)
                    hac[mt][nt] = __builtin_amdgcn_mfma_f32_16x16x32_f16(af, bf[nt], hac[mt][nt], 0, 0, 0);
            }
        }
    }

    float* ob = out + ((size_t)b << 16);
    #pragma unroll
    for (int mt = 0; mt < 4; ++mt)
        #pragma unroll
        for (int nt = 0; nt < 4; ++nt)
            #pragma unroll
            for (int g = 0; g < 4; ++g)
                ob[(size_t)(wv * 64 + mt * 16 + lq * 4 + g) * WDIM + j0 + nt * 16 + lm] = hac[mt][nt][g];
}

// ---------- fallback path (only if ws too small; needs no workspace) ----------
__device__ __forceinline__ int make_weights161(int b, const float* __restrict__ sigmas,
                                               const int* __restrict__ steps,
                                               float* wl, float* red) {
    int t = threadIdx.x;
    float sigma = sigmas[steps[b]];
    float radf = floorf(4.0f * sigma + 0.5f);
    if (t < 192) {
        float w = 0.0f;
        if (t < 161) {
            float off = (float)(t - 80);
            if (fabsf(off) <= radf) { float z = off / sigma; w = expf(-0.5f * z * z); }
        }
        wl[t] = w;
    }
    __syncthreads();
    if (t < 64) {
        float v = wl[t] + wl[t + 64] + wl[t + 128];
        #pragma unroll
        for (int o = 32; o > 0; o >>= 1) v += __shfl_down(v, o);
        if (t == 0) red[0] = 1.0f / v;
    }
    __syncthreads();
    float rs = red[0];
    if (t < 161) wl[t] *= rs;
    __syncthreads();
    return (int)radf;
}

__global__ __launch_bounds__(256) void vblur_nt(const float* __restrict__ in,
                                                float* __restrict__ out,
                                                const float* __restrict__ sigmas,
                                                const int* __restrict__ steps) {
    __shared__ float wl[192];
    __shared__ float red[1];
    int bid = blockIdx.x;
    int b = bid >> 4, i0 = (bid & 15) * 16;
    int rad = make_weights161(b, sigmas, steps, wl, red);
    int j = threadIdx.x;
    const float* inb = in + (size_t)b * WDIM * WDIM;
    float acc[16];
    #pragma unroll
    for (int ii = 0; ii < 16; ++ii) acc[ii] = 0.0f;
    for (int u = -rad; u <= rad; ++u) {
        float w = wl[80 + u];
        #pragma unroll
        for (int ii = 0; ii < 16; ++ii)
            acc[ii] = fmaf(w, inb[reflect(i0 + ii + u) * WDIM + j], acc[ii]);
    }
    #pragma unroll
    for (int ii = 0; ii < 16; ++ii)
        out[((size_t)b * WDIM + (i0 + ii)) * WDIM + j] = acc[ii];
}

__global__ __launch_bounds__(256) void hblur_inplace(float* __restrict__ buf,
                                                     const float* __restrict__ sigmas,
                                                     const int* __restrict__ steps) {
    __shared__ float wl[192];
    __shared__ float red[1];
    __shared__ float rp[WDIM + 160];
    int bid = blockIdx.x;
    int b = bid >> 8, i = bid & 255;
    float* row = buf + ((size_t)b * WDIM + i) * WDIM;
    int t = threadIdx.x;
    for (int s = t; s < WDIM + 160; s += 256) rp[s] = row[reflect(s - 80)];
    int rad = make_weights161(b, sigmas, steps, wl, red);
    float acc = 0.0f;
    for (int u = -rad; u <= rad; ++u) acc = fmaf(wl[80 + u], rp[80 + t + u], acc);
    row[t] = acc;
}
// --------------------------------------------------------------------------------

extern "C" void kernel_launch(void* const* d_in, const int* in_sizes, int n_in,
                              void* d_out, int out_size, void* d_ws, size_t ws_size,
                              hipStream_t stream) {
    const float* x     = (const float*)d_in[0];
    const float* sig   = (const float*)d_in[1];
    const int*   steps = (const int*)d_in[2];
    float* out = (float*)d_out;

    const size_t need = (size_t)WOFF + (size_t)NSIG * WDIM * WDIM * 2;
    if (ws_size >= need) {
        int* q = (int*)d_ws;
        _Float16* Wg = (_Float16*)((char*)d_ws + WOFF);
        build_all<<<257, 256, 0, stream>>>(sig, steps, Wg, q);
        blur_mfma<true><<<NBLK, 256, 0, stream>>>(x, out, sig, steps, q, Wg);
    } else {
        vblur_nt<<<NSAMP * 16, 256, 0, stream>>>(x, out, sig, steps);
        hblur_inplace<<<NSAMP * WDIM, 256, 0, stream>>>(out, sig, steps);
    }
}